// Round 9
// baseline (28.000 us; speedup 1.0000x reference)
//
#include <hip/hip_runtime.h>
#include <math.h>

namespace {

constexpr int kNB    = 16;
constexpr int kFrame = 2048;
constexpr int kHalf  = 16;   // packed stream length (2 streams of 16 = 32 samples/lane)

typedef float f32x2 __attribute__((ext_vector_type(2)));

__device__ inline f32x2 pk_fma(f32x2 a, f32x2 b, f32x2 c) {
    f32x2 d;
    asm("v_pk_fma_f32 %0, %1, %2, %3" : "=v"(d) : "v"(a), "v"(b), "v"(c));
    return d;
}
__device__ inline f32x2 pk_mul(f32x2 a, f32x2 b) {
    f32x2 d;
    asm("v_pk_mul_f32 %0, %1, %2" : "=v"(d) : "v"(a), "v"(b));
    return d;
}
__device__ inline f32x2 pk_add(f32x2 a, f32x2 b) {
    f32x2 d;
    asm("v_pk_add_f32 %0, %1, %2" : "=v"(d) : "v"(a), "v"(b));
    return d;
}

// DPP move with bound_ctrl=1 (out-of-range -> 0)
template <int CTRL>
__device__ inline float dpp_f(float v) {
    return __int_as_float(
        __builtin_amdgcn_update_dpp(0, __float_as_int(v), CTRL, 0xF, 0xF, true));
}

// one uniform-matrix Kogge-Stone level via row_shr DPP (intra-row-16)
template <int CTRL>
__device__ inline void ks_level(float& v0, float& v1, const float4 M, const float na1) {
    const float t0 = dpp_f<CTRL>(v0);
    const float t1 = dpp_f<CTRL>(v1);
    const float w  = fmaf(na1, t0, t1);
    v0 = fmaf(M.x, w,  fmaf(M.y, t0, v0));
    v1 = fmaf(M.z, t0, fmaf(M.y, t1, v1));
}

// Block = 64 threads = 1 wave = 1 channel. Lane owns 32 consecutive samples
// (2 packed streams of 16). Scan across lanes is 100% DPP.
__global__ __launch_bounds__(64)
void biquad_chain_kernel(const float* __restrict__ audio,
                         const float* __restrict__ params,
                         float* __restrict__ out)
{
    // sK[b][0] = (b0, b1, b2, na1); sK[b][1] = (na2, al16, be16, ga16)  [A^16]
    __shared__ float4 sK[kNB][2];
    // powT[b][i] = (al, be, ga, 0) for M^(i+1), M = A^32, i = 0..31 (col 33 pads)
    __shared__ float4 powT[kNB][33];

    const int lane = threadIdx.x & 63;
    const int ch   = blockIdx.x;      // 0..2047
    const int bb   = ch >> 7;
    const int ff   = ch & 127;

    const float* pb = params + (size_t)bb * (50 * 128) + ff;

    // ---- preamble: all 64 lanes; lane -> (band = lane&15, part = lane>>4) ----
    {
        const int band = lane & 15;
        const int part = lane >> 4;
        const float fn = pb[(band * 3 + 0) * 128];
        const float gn = pb[(band * 3 + 1) * 128];
        const float qn = pb[(band * 3 + 2) * 128];

        const bool isHP = (band == 0), isLP = (band == kNB - 1);
        const bool isShelf = (band == 1) || (band == kNB - 2);
        const float flo = isHP ? 2.995732274f
                        : isLP ? 8.517193191f
                        : isShelf ? 3.912023005f
                        : 4.605170186f;
        const float fsp = isHP ? 3.218875825f
                        : isLP ? 1.386294361f
                        : isShelf ? 5.768320996f
                        : 5.010635294f;

        // f32 transcendental block (exp via HW; sin/cos via cancellation-safe
        // half-angle Taylor: ver = 1-cos(w0) = 2*sh^2, sin(w0) = 2*sh*ch)
        const float Q  = __expf(fmaf(qn, 3.465735903f, -0.6931471806f));
        const float fc = __expf(fmaf(fn, fsp, flo));
        const float hw = fc * 3.272492349e-5f;        // pi/96000: w0/2
        const float x2 = hw * hw;
        const float sh = hw * fmaf(x2, fmaf(x2, fmaf(x2, -1.984126984e-4f,
                                   8.333333333e-3f), -0.1666666667f), 1.0f);
        const float chh = sqrtf(fmaf(-sh, sh, 1.0f));
        const float sw  = 2.0f * sh * chh;            // sin(w0)
        const float ver = 2.0f * sh * sh;             // 1 - cos(w0)
        const float alq = sw / (Q + Q);
        const float gdb = (isHP || isLP) ? 0.f : fmaf(gn, 48.f, -24.f);
        const float A   = __expf(gdb * 0.05756462732f);   // ln10/40
        const float sA  = sqrtf(A);
        const float ge  = isHP ? fmaf(pb[48 * 128], 60.f, -60.f) * 0.1151292546f
                        : isLP ? fmaf(pb[49 * 128], 60.f, -60.f) * 0.1151292546f
                        : 0.f;
        const float gm  = __expf(ge);

        float b0, b1, b2, a0, a1, a2;
        if (isHP) {
            b0 = 1.0f - 0.5f * ver; b1 = ver - 2.0f; b2 = b0;
            a0 = 1.0f + alq; a1 = 2.0f * ver - 2.0f; a2 = 1.0f - alq;
        } else if (isLP) {
            b0 = 0.5f * ver; b1 = ver; b2 = b0;
            a0 = 1.0f + alq; a1 = 2.0f * ver - 2.0f; a2 = 1.0f - alq;
        } else if (band == 1) {                // low shelf (ver form)
            const float t = 2.0f * sA * alq;
            const float u = (A - 1.0f) * ver;
            const float w = (A + 1.0f) * ver;
            b0 = A * (2.0f + u + t);
            b1 = A * (2.0f * w - 4.0f);
            b2 = A * (2.0f + u - t);
            a0 = 2.0f * A - u + t;
            a1 = 2.0f * w - 4.0f * A;
            a2 = 2.0f * A - u - t;
        } else if (band == kNB - 2) {          // high shelf (ver form)
            const float t = 2.0f * sA * alq;
            const float u = (A - 1.0f) * ver;
            const float w = (A + 1.0f) * ver;
            b0 = A * (2.0f * A - u + t);
            b1 = -2.0f * A * (2.0f * A - w);
            b2 = A * (2.0f * A - u - t);
            a0 = 2.0f + u + t;
            a1 = 2.0f * w - 4.0f;
            a2 = 2.0f + u - t;
        } else {                               // peaking
            const float alA  = alq * A;
            const float aloA = alq / A;
            b0 = 1.0f + alA; b1 = 2.0f * ver - 2.0f; b2 = 1.0f - alA;
            a0 = 1.0f + aloA; a1 = b1; a2 = 1.0f - aloA;
        }
        const float inv  = 1.0f / a0;
        const float binv = inv * gm;
        b0 *= binv; b1 *= binv; b2 *= binv;
        a1 *= inv; a2 *= inv;

        // f64 CH doubling chain on the f32-rounded (a1, a2)
        const double a1d = (double)a1, a2d = (double)a2;
        double alc = 1.0, bec = 0.0;
        double al16 = 0, be16 = 0, al32 = 0, be32 = 0;
        double al256 = 0, be256 = 0, al512 = 0, be512 = 0;
        #pragma unroll
        for (int k = 1; k <= 9; ++k) {
            const double a_ = alc, b_ = bec;
            alc = a_ * (2.0 * b_ - a1d * a_);
            bec = b_ * b_ - a2d * (a_ * a_);
            if (k == 4) { al16 = alc; be16 = bec; }
            if (k == 5) { al32 = alc; be32 = bec; }
            if (k == 8) { al256 = alc; be256 = bec; }
            if (k == 9) { al512 = alc; be512 = bec; }
        }
        auto cmp = [&](double alx, double bex, double aly, double bey,
                       double& alo, double& beo) {
            const double p = alx * aly;
            alo = alx * bey + bex * aly - a1d * p;
            beo = bex * bey - a2d * p;
        };

        // part start: S = M^(8*part+1), M = A^32
        double Sa, Sb;
        if (part == 0)      { Sa = al32; Sb = be32; }
        else if (part == 1) { cmp(al256, be256, al32, be32, Sa, Sb); }
        else if (part == 2) { cmp(al512, be512, al32, be32, Sa, Sb); }
        else { double ta, tb; cmp(al512, be512, al256, be256, ta, tb);
               cmp(ta, tb, al32, be32, Sa, Sb); }

        #pragma unroll
        for (int j = 0; j < 8; ++j) {
            powT[band][8 * part + j] =
                float4{(float)Sa, (float)Sb, (float)(-a2d * Sa), 0.f};
            double na, nb;
            cmp(Sa, Sb, al32, be32, na, nb);
            Sa = na; Sb = nb;
        }
        if (part == 0) {
            sK[band][0] = float4{b0, b1, b2, -a1};
            sK[band][1] = float4{-a2, (float)al16, (float)be16,
                                 (float)(-a2d * al16)};
        }
    }
    __syncthreads();

    // ---- load 32 samples, pack as 2 streams of 16: X[t] = (x[t], x[t+16]) ----
    f32x2 X[kHalf];
    {
        const float4* ap = reinterpret_cast<const float4*>(
            audio + (size_t)ch * kFrame + lane * 32);
        #pragma unroll
        for (int k = 0; k < 4; ++k) {
            const float4 va = ap[k];
            const float4 vb = ap[k + 4];
            X[4 * k + 0] = f32x2{va.x, vb.x};
            X[4 * k + 1] = f32x2{va.y, vb.y};
            X[4 * k + 2] = f32x2{va.z, vb.z};
            X[4 * k + 3] = f32x2{va.w, vb.w};
        }
    }

    // ---- band 0 coefficients + peeled phase 1 ----
    float4 k0 = sK[0][0], k1 = sK[0][1];
    f32x2 b0p  = {k0.x, k0.x}, b1p = {k0.y, k0.y}, b2p = {k0.z, k0.z};
    f32x2 na1p = {k0.w, k0.w}, na2p = {k1.x, k1.x};

    f32x2 s1 = {0.f, 0.f}, s2 = {0.f, 0.f};
    #pragma unroll
    for (int t = 0; t < kHalf; ++t) {
        const f32x2 xv = X[t];
        const f32x2 y  = pk_fma(b0p, xv, s1);
        const f32x2 tm = pk_fma(b1p, xv, s2);
        s2 = pk_fma(na2p, y, pk_mul(b2p, xv));
        s1 = pk_fma(na1p, y, tm);
        X[t] = y;
    }

    // ---- cascade: scan(band) then fused correction(band)+phase1(band+1) ----
    for (int band = 0; band < kNB; ++band) {
        const float na1 = na1p.x;
        const float al16 = k1.y, be16 = k1.z, ga16 = k1.w;

        const float4 P1 = powT[band][0];
        const float4 P2 = powT[band][1];
        const float4 P4 = powT[band][3];
        const float4 P8 = powT[band][7];
        const float4 Pme = powT[band][lane & 15];   // M^((lane&15)+1)
        const float4 Qme = powT[band][lane & 31];   // M^((lane&31)+1)

        // fold streams with A^16: d = A^16*dA + dB
        const float wf = fmaf(na1, s1.x, s2.x);
        const float d0 = fmaf(al16, wf, fmaf(be16, s1.x, s1.y));
        const float d1 = fmaf(ga16, s1.x, fmaf(be16, s2.x, s2.y));

        // DS-free exclusive affine scan over 64 chunks, M = A^32
        float v0 = dpp_f<0x138>(d0);     // wave_shr:1 (lane 0 -> 0)
        float v1 = dpp_f<0x138>(d1);
        ks_level<0x111>(v0, v1, P1, na1);
        ks_level<0x112>(v0, v1, P2, na1);
        ks_level<0x114>(v0, v1, P4, na1);
        ks_level<0x118>(v0, v1, P8, na1);
        {   // row_bcast15 with per-lane power
            float t0 = dpp_f<0x142>(v0);
            float t1 = dpp_f<0x142>(v1);
            const bool g = (lane & 16) != 0;
            t0 = g ? t0 : 0.f;
            t1 = g ? t1 : 0.f;
            const float w = fmaf(na1, t0, t1);
            v0 = fmaf(Pme.x, w,  fmaf(Pme.y, t0, v0));
            v1 = fmaf(Pme.z, t0, fmaf(Pme.y, t1, v1));
        }
        {   // row_bcast31 with per-lane power
            float t0 = dpp_f<0x143>(v0);
            float t1 = dpp_f<0x143>(v1);
            const bool g = lane >= 32;
            t0 = g ? t0 : 0.f;
            t1 = g ? t1 : 0.f;
            const float w = fmaf(na1, t0, t1);
            v0 = fmaf(Qme.x, w,  fmaf(Qme.y, t0, v0));
            v1 = fmaf(Qme.z, t0, fmaf(Qme.y, t1, v1));
        }

        // reconstruct stream-B incoming: uB = A^16*u + dA
        const float wr  = fmaf(na1, v0, v1);
        const float uB0 = fmaf(al16, wr, fmaf(be16, v0, s1.x));
        const float uB1 = fmaf(ga16, v0, fmaf(be16, v1, s2.x));
        f32x2 cw0 = {v0, uB0}, cw1 = {v1, uB1};

        if (band == kNB - 1) {
            // final correction fused into X, then store
            #pragma unroll
            for (int t = 0; t < kHalf; ++t) {
                const f32x2 cc = cw0;
                X[t] = pk_add(X[t], cc);
                cw0 = pk_fma(na1p, cc, cw1);
                cw1 = pk_mul(na2p, cc);
            }
            break;
        }

        // next band coefficients
        const float4 nk0 = sK[band + 1][0];
        const float4 nk1 = sK[band + 1][1];
        const f32x2 nb0p  = {nk0.x, nk0.x}, nb1p = {nk0.y, nk0.y};
        const f32x2 nb2p  = {nk0.z, nk0.z};
        const f32x2 nna1p = {nk0.w, nk0.w}, nna2p = {nk1.x, nk1.x};

        // fused: correction(band) evolves under current A; filter with band+1
        s1 = f32x2{0.f, 0.f}; s2 = f32x2{0.f, 0.f};
        #pragma unroll
        for (int t = 0; t < kHalf; ++t) {
            const f32x2 cc = cw0;
            cw0 = pk_fma(na1p, cc, cw1);
            cw1 = pk_mul(na2p, cc);
            const f32x2 xv = pk_add(X[t], cc);
            const f32x2 y  = pk_fma(nb0p, xv, s1);
            const f32x2 tm = pk_fma(nb1p, xv, s2);
            s2 = pk_fma(nna2p, y, pk_mul(nb2p, xv));
            s1 = pk_fma(nna1p, y, tm);
            X[t] = y;
        }

        // rotate coefficients
        k0 = nk0; k1 = nk1;
        b0p = nb0p; b1p = nb1p; b2p = nb2p; na1p = nna1p; na2p = nna2p;
    }

    // ---- unpack + store ----
    {
        float4* op = reinterpret_cast<float4*>(out + (size_t)ch * kFrame + lane * 32);
        #pragma unroll
        for (int k = 0; k < 4; ++k) {
            op[k]     = float4{X[4 * k + 0].x, X[4 * k + 1].x, X[4 * k + 2].x, X[4 * k + 3].x};
            op[k + 4] = float4{X[4 * k + 0].y, X[4 * k + 1].y, X[4 * k + 2].y, X[4 * k + 3].y};
        }
    }
}

} // namespace

extern "C" void kernel_launch(void* const* d_in, const int* in_sizes, int n_in,
                              void* d_out, int out_size, void* d_ws, size_t ws_size,
                              hipStream_t stream)
{
    (void)d_ws; (void)ws_size; (void)n_in; (void)in_sizes;
    const float* audio  = (const float*)d_in[0];
    const float* params = (const float*)d_in[1];
    float* outp = (float*)d_out;

    const int channels = out_size / kFrame;        // 2048
    hipLaunchKernelGGL(biquad_chain_kernel, dim3(channels), dim3(64), 0, stream,
                       audio, params, outp);
}

// Round 10
// 27.054 us; speedup vs baseline: 1.0350x; 1.0350x over previous
//
#include <hip/hip_runtime.h>
#include <math.h>

namespace {

constexpr int kNB    = 16;
constexpr int kFrame = 2048;
constexpr int kHalf  = 16;   // packed stream length (2 streams of 16 = 32 samples/lane)

typedef float f32x2 __attribute__((ext_vector_type(2)));

__device__ inline f32x2 pk_fma(f32x2 a, f32x2 b, f32x2 c) {
    f32x2 d;
    asm("v_pk_fma_f32 %0, %1, %2, %3" : "=v"(d) : "v"(a), "v"(b), "v"(c));
    return d;
}
__device__ inline f32x2 pk_mul(f32x2 a, f32x2 b) {
    f32x2 d;
    asm("v_pk_mul_f32 %0, %1, %2" : "=v"(d) : "v"(a), "v"(b));
    return d;
}
__device__ inline f32x2 pk_add(f32x2 a, f32x2 b) {
    f32x2 d;
    asm("v_pk_add_f32 %0, %1, %2" : "=v"(d) : "v"(a), "v"(b));
    return d;
}

// DPP move with bound_ctrl=1 (out-of-range -> 0)
template <int CTRL>
__device__ inline float dpp_f(float v) {
    return __int_as_float(
        __builtin_amdgcn_update_dpp(0, __float_as_int(v), CTRL, 0xF, 0xF, true));
}

// one uniform-matrix Kogge-Stone level via row_shr DPP (intra-row-16)
template <int CTRL>
__device__ inline void ks_level(float& v0, float& v1, const float4 M, const float na1) {
    const float t0 = dpp_f<CTRL>(v0);
    const float t1 = dpp_f<CTRL>(v1);
    const float w  = fmaf(na1, t0, t1);
    v0 = fmaf(M.x, w,  fmaf(M.y, t0, v0));
    v1 = fmaf(M.z, t0, fmaf(M.y, t1, v1));
}

// Block = 64 threads = 1 wave = 1 channel. Lane owns 32 consecutive samples
// (2 packed streams of 16). Scan across lanes is 100% DPP.
__global__ __launch_bounds__(64)
void biquad_chain_kernel(const float* __restrict__ audio,
                         const float* __restrict__ params,
                         float* __restrict__ out)
{
    // sK[b][0] = (b0, b1, b2, na1); sK[b][1] = (na2, al16, be16, ga16)  [A^16]
    __shared__ float4 sK[kNB][2];
    // powT[b][i] = (al, be, ga, 0) for M^(i+1), M = A^32, i = 0..31 (col 33 pads)
    __shared__ float4 powT[kNB][33];

    const int lane = threadIdx.x & 63;
    const int ch   = blockIdx.x;      // 0..2047
    const int bb   = ch >> 7;
    const int ff   = ch & 127;

    const float* pb = params + (size_t)bb * (50 * 128) + ff;

    // ---- hoisted audio load: HBM latency hides under the preamble ----
    // pack as 2 streams of 16: X[t] = (x[t], x[t+16])
    f32x2 X[kHalf];
    {
        const float4* ap = reinterpret_cast<const float4*>(
            audio + (size_t)ch * kFrame + lane * 32);
        #pragma unroll
        for (int k = 0; k < 4; ++k) {
            const float4 va = ap[k];
            const float4 vb = ap[k + 4];
            X[4 * k + 0] = f32x2{va.x, vb.x};
            X[4 * k + 1] = f32x2{va.y, vb.y};
            X[4 * k + 2] = f32x2{va.z, vb.z};
            X[4 * k + 3] = f32x2{va.w, vb.w};
        }
    }

    // ---- preamble: all 64 lanes; lane -> (band = lane&15, part = lane>>4) ----
    {
        const int band = lane & 15;
        const int part = lane >> 4;
        const float fn = pb[(band * 3 + 0) * 128];
        const float gn = pb[(band * 3 + 1) * 128];
        const float qn = pb[(band * 3 + 2) * 128];

        const bool isHP = (band == 0), isLP = (band == kNB - 1);
        const bool isShelf = (band == 1) || (band == kNB - 2);
        const float flo = isHP ? 2.995732274f
                        : isLP ? 8.517193191f
                        : isShelf ? 3.912023005f
                        : 4.605170186f;
        const float fsp = isHP ? 3.218875825f
                        : isLP ? 1.386294361f
                        : isShelf ? 5.768320996f
                        : 5.010635294f;

        // f32 transcendental block (exp via HW; sin/cos via cancellation-safe
        // half-angle Taylor: ver = 1-cos(w0) = 2*sh^2, sin(w0) = 2*sh*ch)
        const float Q  = __expf(fmaf(qn, 3.465735903f, -0.6931471806f));
        const float fc = __expf(fmaf(fn, fsp, flo));
        const float hw = fc * 3.272492349e-5f;        // pi/96000: w0/2
        const float x2 = hw * hw;
        const float sh = hw * fmaf(x2, fmaf(x2, fmaf(x2, -1.984126984e-4f,
                                   8.333333333e-3f), -0.1666666667f), 1.0f);
        const float chh = sqrtf(fmaf(-sh, sh, 1.0f));
        const float sw  = 2.0f * sh * chh;            // sin(w0)
        const float ver = 2.0f * sh * sh;             // 1 - cos(w0)
        const float alq = sw / (Q + Q);
        const float gdb = (isHP || isLP) ? 0.f : fmaf(gn, 48.f, -24.f);
        const float A   = __expf(gdb * 0.05756462732f);   // ln10/40
        const float sA  = sqrtf(A);
        const float ge  = isHP ? fmaf(pb[48 * 128], 60.f, -60.f) * 0.1151292546f
                        : isLP ? fmaf(pb[49 * 128], 60.f, -60.f) * 0.1151292546f
                        : 0.f;
        const float gm  = __expf(ge);

        float b0, b1, b2, a0, a1, a2;
        if (isHP) {
            b0 = 1.0f - 0.5f * ver; b1 = ver - 2.0f; b2 = b0;
            a0 = 1.0f + alq; a1 = 2.0f * ver - 2.0f; a2 = 1.0f - alq;
        } else if (isLP) {
            b0 = 0.5f * ver; b1 = ver; b2 = b0;
            a0 = 1.0f + alq; a1 = 2.0f * ver - 2.0f; a2 = 1.0f - alq;
        } else if (band == 1) {                // low shelf (ver form)
            const float t = 2.0f * sA * alq;
            const float u = (A - 1.0f) * ver;
            const float w = (A + 1.0f) * ver;
            b0 = A * (2.0f + u + t);
            b1 = A * (2.0f * w - 4.0f);
            b2 = A * (2.0f + u - t);
            a0 = 2.0f * A - u + t;
            a1 = 2.0f * w - 4.0f * A;
            a2 = 2.0f * A - u - t;
        } else if (band == kNB - 2) {          // high shelf (ver form)
            const float t = 2.0f * sA * alq;
            const float u = (A - 1.0f) * ver;
            const float w = (A + 1.0f) * ver;
            b0 = A * (2.0f * A - u + t);
            b1 = -2.0f * A * (2.0f * A - w);
            b2 = A * (2.0f * A - u - t);
            a0 = 2.0f + u + t;
            a1 = 2.0f * w - 4.0f;
            a2 = 2.0f + u - t;
        } else {                               // peaking
            const float alA  = alq * A;
            const float aloA = alq / A;
            b0 = 1.0f + alA; b1 = 2.0f * ver - 2.0f; b2 = 1.0f - alA;
            a0 = 1.0f + aloA; a1 = b1; a2 = 1.0f - aloA;
        }
        const float inv  = 1.0f / a0;
        const float binv = inv * gm;
        b0 *= binv; b1 *= binv; b2 *= binv;
        a1 *= inv; a2 *= inv;

        // f64 CH doubling chain on the f32-rounded (a1, a2)
        const double a1d = (double)a1, a2d = (double)a2;
        double alc = 1.0, bec = 0.0;
        double al16 = 0, be16 = 0, al32 = 0, be32 = 0;
        double al256 = 0, be256 = 0, al512 = 0, be512 = 0;
        #pragma unroll
        for (int k = 1; k <= 9; ++k) {
            const double a_ = alc, b_ = bec;
            alc = a_ * (2.0 * b_ - a1d * a_);
            bec = b_ * b_ - a2d * (a_ * a_);
            if (k == 4) { al16 = alc; be16 = bec; }
            if (k == 5) { al32 = alc; be32 = bec; }
            if (k == 8) { al256 = alc; be256 = bec; }
            if (k == 9) { al512 = alc; be512 = bec; }
        }
        auto cmp = [&](double alx, double bex, double aly, double bey,
                       double& alo, double& beo) {
            const double p = alx * aly;
            alo = alx * bey + bex * aly - a1d * p;
            beo = bex * bey - a2d * p;
        };

        // part start: S = M^(8*part+1), M = A^32
        double Sa, Sb;
        if (part == 0)      { Sa = al32; Sb = be32; }
        else if (part == 1) { cmp(al256, be256, al32, be32, Sa, Sb); }
        else if (part == 2) { cmp(al512, be512, al32, be32, Sa, Sb); }
        else { double ta, tb; cmp(al512, be512, al256, be256, ta, tb);
               cmp(ta, tb, al32, be32, Sa, Sb); }

        #pragma unroll
        for (int j = 0; j < 8; ++j) {
            powT[band][8 * part + j] =
                float4{(float)Sa, (float)Sb, (float)(-a2d * Sa), 0.f};
            double na, nb;
            cmp(Sa, Sb, al32, be32, na, nb);
            Sa = na; Sb = nb;
        }
        if (part == 0) {
            sK[band][0] = float4{b0, b1, b2, -a1};
            sK[band][1] = float4{-a2, (float)al16, (float)be16,
                                 (float)(-a2d * al16)};
        }
    }
    __syncthreads();

    // ---- cascade ----
    for (int band = 0; band < kNB; ++band) {
        const float4 k0 = sK[band][0];
        const float4 k1 = sK[band][1];
        const float4 P1 = powT[band][0];
        const float4 P2 = powT[band][1];
        const float4 P4 = powT[band][3];
        const float4 P8 = powT[band][7];
        const float4 Pme = powT[band][lane & 15];   // M^((lane&15)+1)
        const float4 Qme = powT[band][lane & 31];   // M^((lane&31)+1)

        const float b0 = k0.x, b1 = k0.y, b2 = k0.z, na1 = k0.w;
        const float na2 = k1.x, al16 = k1.y, be16 = k1.z, ga16 = k1.w;
        const f32x2 b0p  = {b0, b0},  b1p = {b1, b1}, b2p = {b2, b2};
        const f32x2 na1p = {na1, na1}, na2p = {na2, na2};

        // phase 1: two independent zero-state 16-sample streams (packed)
        f32x2 s1 = {0.f, 0.f}, s2 = {0.f, 0.f};
        #pragma unroll
        for (int t = 0; t < kHalf; ++t) {
            const f32x2 xv = X[t];
            const f32x2 y  = pk_fma(b0p, xv, s1);
            const f32x2 tm = pk_fma(b1p, xv, s2);
            s2 = pk_fma(na2p, y, pk_mul(b2p, xv));
            s1 = pk_fma(na1p, y, tm);
            X[t] = y;
        }

        // fold streams with A^16: d = A^16*dA + dB
        const float wf = fmaf(na1, s1.x, s2.x);
        const float d0 = fmaf(al16, wf, fmaf(be16, s1.x, s1.y));
        const float d1 = fmaf(ga16, s1.x, fmaf(be16, s2.x, s2.y));

        // ---- DS-free exclusive affine scan over 64 chunks, M = A^32 ----
        float v0 = dpp_f<0x138>(d0);     // wave_shr:1 (lane 0 -> 0)
        float v1 = dpp_f<0x138>(d1);
        ks_level<0x111>(v0, v1, P1, na1);
        ks_level<0x112>(v0, v1, P2, na1);
        ks_level<0x114>(v0, v1, P4, na1);
        ks_level<0x118>(v0, v1, P8, na1);
        {   // row_bcast15 with per-lane power
            float t0 = dpp_f<0x142>(v0);
            float t1 = dpp_f<0x142>(v1);
            const bool g = (lane & 16) != 0;
            t0 = g ? t0 : 0.f;
            t1 = g ? t1 : 0.f;
            const float w = fmaf(na1, t0, t1);
            v0 = fmaf(Pme.x, w,  fmaf(Pme.y, t0, v0));
            v1 = fmaf(Pme.z, t0, fmaf(Pme.y, t1, v1));
        }
        {   // row_bcast31 with per-lane power
            float t0 = dpp_f<0x143>(v0);
            float t1 = dpp_f<0x143>(v1);
            const bool g = lane >= 32;
            t0 = g ? t0 : 0.f;
            t1 = g ? t1 : 0.f;
            const float w = fmaf(na1, t0, t1);
            v0 = fmaf(Qme.x, w,  fmaf(Qme.y, t0, v0));
            v1 = fmaf(Qme.z, t0, fmaf(Qme.y, t1, v1));
        }

        // reconstruct stream-B incoming: uB = A^16*u + dA
        const float wr  = fmaf(na1, v0, v1);
        const float uB0 = fmaf(al16, wr, fmaf(be16, v0, s1.x));
        const float uB1 = fmaf(ga16, v0, fmaf(be16, v1, s2.x));

        // phase 2: packed homogeneous correction y(t) += [A^t * u]_0
        f32x2 w0 = {v0, uB0}, w1 = {v1, uB1};
        #pragma unroll
        for (int t = 0; t < kHalf; ++t) {
            const f32x2 c = w0;
            X[t] = pk_add(X[t], c);
            w0 = pk_fma(na1p, c, w1);
            w1 = pk_mul(na2p, c);
        }
    }

    // ---- unpack + store ----
    {
        float4* op = reinterpret_cast<float4*>(out + (size_t)ch * kFrame + lane * 32);
        #pragma unroll
        for (int k = 0; k < 4; ++k) {
            op[k]     = float4{X[4 * k + 0].x, X[4 * k + 1].x, X[4 * k + 2].x, X[4 * k + 3].x};
            op[k + 4] = float4{X[4 * k + 0].y, X[4 * k + 1].y, X[4 * k + 2].y, X[4 * k + 3].y};
        }
    }
}

} // namespace

extern "C" void kernel_launch(void* const* d_in, const int* in_sizes, int n_in,
                              void* d_out, int out_size, void* d_ws, size_t ws_size,
                              hipStream_t stream)
{
    (void)d_ws; (void)ws_size; (void)n_in; (void)in_sizes;
    const float* audio  = (const float*)d_in[0];
    const float* params = (const float*)d_in[1];
    float* outp = (float*)d_out;

    const int channels = out_size / kFrame;        // 2048
    hipLaunchKernelGGL(biquad_chain_kernel, dim3(channels), dim3(64), 0, stream,
                       audio, params, outp);
}